// Round 11
// baseline (30.297 us; speedup 1.0000x reference)
//
#include <hip/hip_runtime.h>
#include <hip/hip_bf16.h>

// KANLinear as bf16 MFMA GEMM, K = i*8 + c (c: spline q=2..7 pre-scaled 1/6,
// silu, pad). Round 11: R10 + per-wave kt-rotation to break wave lockstep.
//  - A chunk = 4 kt (32KB) double-buffered; staging interleaved into K-loop;
//    one barrier per chunk. (R10, unchanged)
//  - NEW: wave w processes its chunk's 4 kts in rotated order
//    kt = c*4 + ((ktl + (wv&3)) & 3) — MFMA accumulation order over kt is
//    free, the whole chunk is LDS-resident. Different wave-groups are at
//    different phases => ds_read / MFMA / phi+ds_write overlap across waves
//    instead of bursting in lockstep.
//  - B register-double-buffered along each wave's OWN rotated sequence
//    (breg parity indices remain compile-time static).
//  - 512 thr / 8 waves (8 col groups, wave tile 64x32), grid 256 = 1 block/CU.

#define M_TOTAL 16384
#define IF 256
#define OF 256
#define NKT 32
#define THREADS 512

typedef __attribute__((ext_vector_type(8))) __bf16 bf16x8;
typedef __attribute__((ext_vector_type(4))) float f32x4;

// Image: 16B unit index = frag*64 + lane; frag = kt*32 + ks*16 + wn*2 + n.
// Fragment (kt,ks,wn,n), lane: col = wn*32 + n*16 + (lane&15),
// i = kt*8 + ks*4 + (lane>>4), 8 c-slots per unit.
__global__ void repack_w(const float* __restrict__ w, __bf16* __restrict__ img) {
    int g = blockIdx.x * 256 + threadIdx.x;      // 0..65535
    int lane = g & 63, frag = g >> 6;
    int n  = frag & 1;
    int wn = (frag >> 1) & 7;
    int ks = (frag >> 4) & 1;
    int kt = frag >> 5;
    int col = wn * 32 + n * 16 + (lane & 15);
    int i   = kt * 8 + ks * 4 + (lane >> 4);
    const float s6 = 1.0f / 6.0f;
    bf16x8 v;
#pragma unroll
    for (int c = 0; c < 8; ++c) {
        float f = (c < 6) ? w[(size_t)i * 2304 + col * 9 + c + 2] * s6
                : (c == 6) ? w[(size_t)i * 2304 + col * 9 + 8] : 0.0f;
        v[c] = (__bf16)f;
    }
    ((bf16x8*)img)[g] = v;
}

// one x -> A-fragment {shift-selected cubic B-spline pieces, silu, 0}
__device__ __forceinline__ bf16x8 phi_pack(float x) {
    float t  = fmaf(x, 2.5f, 5.5f);
    float fi = floorf(t);                // 5,6,7 for x in [0,1)
    float u  = (t - fi) - 3.0f;          // [-3,-2)
    float u2 = u * u, u3 = u2 * u;
    float w0 = fmaf(-1.f, u3, fmaf( 3.f, u2, fmaf(-3.f, u, 1.f)));
    float w1 = fmaf( 3.f, u3, fmaf(-6.f, u2, 4.f));
    float w2 = fmaf(-3.f, u3, fmaf( 3.f, u2, fmaf( 3.f, u, 1.f)));
    float w3 = u3;
    bool e1 = fi > 5.5f;                 // idx >= 6
    bool e2 = fi > 6.5f;                 // idx == 7
    float v0 = e1 ? 0.f : w0;
    float v1 = e2 ? 0.f : (e1 ? w0 : w1);
    float v2 = e2 ? w0  : (e1 ? w1 : w2);
    float v3 = e2 ? w1  : (e1 ? w2 : w3);
    float v4 = e2 ? w2  : (e1 ? w3 : 0.f);
    float v5 = e2 ? w3  : 0.f;
    float sl = x * __builtin_amdgcn_rcpf(1.f + __expf(-x));
    bf16x8 v;
    v[0] = (__bf16)v0; v[1] = (__bf16)v1; v[2] = (__bf16)v2; v[3] = (__bf16)v3;
    v[4] = (__bf16)v4; v[5] = (__bf16)v5; v[6] = (__bf16)sl; v[7] = (__bf16)0.f;
    return v;
}

// Slow-path gather of one B fragment directly from W (used only if ws absent).
__device__ __forceinline__ bf16x8 gather_frag(const float* __restrict__ W,
                                              int kt, int wn, int ks, int n, int lane) {
    int col = wn * 32 + n * 16 + (lane & 15);
    int i   = kt * 8 + ks * 4 + (lane >> 4);
    const float s6 = 1.0f / 6.0f;
    bf16x8 v;
#pragma unroll
    for (int c = 0; c < 8; ++c) {
        float f = (c < 6) ? W[(size_t)i * 2304 + col * 9 + c + 2] * s6
                : (c == 6) ? W[(size_t)i * 2304 + col * 9 + 8] : 0.0f;
        v[c] = (__bf16)f;
    }
    return v;
}

template <bool DIRECT_B>
__global__ __launch_bounds__(THREADS, 2)
void kan_gemm(const float* __restrict__ X, const __bf16* __restrict__ Bimg,
              const float* __restrict__ W, float* __restrict__ Y) {
    // A dbuf: 2 x (64 rows x 512B) = 64KB. Row layout: 32 chunks of 16B,
    // chunk index XOR-swizzled with row&7.
    __shared__ alignas(16) char lds[65536];

    const int tid  = threadIdx.x;
    const int lane = tid & 63;
    const int wn   = tid >> 6;       // col group 0..7 (32 cols)
    const int rot  = wn & 3;         // per-wave kt rotation within chunk
    const int l15  = lane & 15;
    const int l4   = lane >> 4;
    const int brow0 = blockIdx.x * 64;

    // phi staging: row = tid>>3, i-slot within chunk = ktl*8 + (tid&7)
    const int prow = tid >> 3;           // 0..63
    const int pi   = tid & 7;            // 0..7
    const int pr7  = prow & 7;
    const float* xrow = X + (size_t)(brow0 + prow) * IF;
    const int awbase = prow * 512;

    // A-frag read swizzle: (m*16+l15)&7 == l15&7
    const int sw = l15 & 7;

    // B image base for this wave's column group
    const char* ib = (const char*)Bimg + wn * 2048 + lane * 16;
    // + kt*32768 + ks*16384 + n*1024

    f32x4 acc[4][2] = {};
    bf16x8 breg[2][4];       // [step parity][ks*2+n], parity always static
    float xs[4];

    // ---- prologue ----
    // x for chunk 0 staging
#pragma unroll
    for (int w = 0; w < 4; ++w) xs[w] = xrow[w * 8 + pi];
    // B for this wave's FIRST kt in rotated order (kt = rot) -> breg[0]
    if (!DIRECT_B) {
        const char* p = ib + (size_t)rot * 32768;
        breg[0][0] = *(const bf16x8*)(p);
        breg[0][1] = *(const bf16x8*)(p + 1024);
        breg[0][2] = *(const bf16x8*)(p + 16384);
        breg[0][3] = *(const bf16x8*)(p + 17408);
    } else {
        breg[0][0] = gather_frag(W, rot, wn, 0, 0, lane);
        breg[0][1] = gather_frag(W, rot, wn, 0, 1, lane);
        breg[0][2] = gather_frag(W, rot, wn, 1, 0, lane);
        breg[0][3] = gather_frag(W, rot, wn, 1, 1, lane);
    }
    // stage chunk 0 into buf 0
#pragma unroll
    for (int w = 0; w < 4; ++w)
        *(bf16x8*)(lds + awbase + (((w * 8 + pi) ^ pr7) << 4)) = phi_pack(xs[w]);
    // x for chunk 1 staging (staged during chunk 0)
#pragma unroll
    for (int w = 0; w < 4; ++w) xs[w] = xrow[32 + w * 8 + pi];
    __syncthreads();

    for (int c = 0; c < 8; ++c) {
        const char* Ar = lds + ((c & 1) << 15);
        char* Aw = lds + (((c + 1) & 1) << 15);

#pragma unroll
        for (int ktl = 0; ktl < 4; ++ktl) {
            // this wave's rotated K-step within the chunk
            const int kte = (ktl + rot) & 3;             // effective ktl
            // next K-step in THIS wave's sequence (for B prefetch)
            const int ktn = (ktl < 3) ? (c * 4 + ((ktl + 1 + rot) & 3))
                          : ((c < 7) ? ((c + 1) * 4 + rot)
                                     : (c * 4 + kte));   // clamp at end

            // ---- B prefetch into breg[(ktl+1)&1] (static parity) ----
            if (!DIRECT_B) {
                const char* p = ib + (size_t)ktn * 32768;
                breg[(ktl + 1) & 1][0] = *(const bf16x8*)(p);
                breg[(ktl + 1) & 1][1] = *(const bf16x8*)(p + 1024);
                breg[(ktl + 1) & 1][2] = *(const bf16x8*)(p + 16384);
                breg[(ktl + 1) & 1][3] = *(const bf16x8*)(p + 17408);
            } else {
                breg[(ktl + 1) & 1][0] = gather_frag(W, ktn, wn, 0, 0, lane);
                breg[(ktl + 1) & 1][1] = gather_frag(W, ktn, wn, 0, 1, lane);
                breg[(ktl + 1) & 1][2] = gather_frag(W, ktn, wn, 1, 0, lane);
                breg[(ktl + 1) & 1][3] = gather_frag(W, ktn, wn, 1, 1, lane);
            }

            // ---- A-fragment reads for this wave's current K-step ----
            bf16x8 aF[4][2];
#pragma unroll
            for (int m = 0; m < 4; ++m)
#pragma unroll
                for (int ks = 0; ks < 2; ++ks)
                    aF[m][ks] = *(const bf16x8*)(Ar + (m * 16 + l15) * 512
                                    + (((kte * 8 + ks * 4 + l4) ^ sw) << 4));

            // ---- MFMA cluster ----
            __builtin_amdgcn_s_setprio(1);
#pragma unroll
            for (int ks = 0; ks < 2; ++ks)
#pragma unroll
                for (int m = 0; m < 4; ++m)
#pragma unroll
                    for (int n = 0; n < 2; ++n)
                        acc[m][n] = __builtin_amdgcn_mfma_f32_16x16x32_bf16(
                            aF[m][ks], breg[ktl & 1][ks * 2 + n], acc[m][n], 0, 0, 0);
            __builtin_amdgcn_s_setprio(0);

            // ---- interleaved staging of chunk c+1 (1 phi per step) ----
            if (c < 7) {
                *(bf16x8*)(Aw + awbase + (((ktl * 8 + pi) ^ pr7) << 4))
                    = phi_pack(xs[ktl]);
                // refill xs[ktl] with x for chunk c+2's staging
                if (c < 6) xs[ktl] = xrow[(c + 2) * 32 + ktl * 8 + pi];
            }
        }
        __syncthreads();
    }

    // ---- epilogue: C/D layout col=lane&15, row=(lane>>4)*4+r ----
#pragma unroll
    for (int m = 0; m < 4; ++m)
#pragma unroll
        for (int n = 0; n < 2; ++n) {
            int col  = wn * 32 + n * 16 + l15;
            int row0 = brow0 + m * 16 + l4 * 4;
#pragma unroll
            for (int r = 0; r < 4; ++r)
                Y[(size_t)(row0 + r) * OF + col] = acc[m][n][r];
        }
}

extern "C" void kernel_launch(void* const* d_in, const int* in_sizes, int n_in,
                              void* d_out, int out_size, void* d_ws, size_t ws_size,
                              hipStream_t stream) {
    const float* X = (const float*)d_in[0];
    const float* W = (const float*)d_in[1];
    float* Y = (float*)d_out;

    size_t need = (size_t)65536 * 16;                   // 1.0 MB image
    dim3 grid(M_TOTAL / 64);                            // 256 blocks, 1/CU

    if (d_ws != nullptr && ws_size >= need) {
        __bf16* img = (__bf16*)d_ws;
        repack_w<<<dim3(256), dim3(256), 0, stream>>>(W, img);
        kan_gemm<false><<<grid, dim3(THREADS), 0, stream>>>(X, img, W, Y);
    } else {
        kan_gemm<true><<<grid, dim3(THREADS), 0, stream>>>(X, nullptr, W, Y);
    }
}